// Round 20
// baseline (174.627 us; speedup 1.0000x reference)
//
#include <hip/hip_runtime.h>
#include <hip/hip_bf16.h>

// Problem constants
#define Bq 32
#define Lq 256
#define Hq 8
#define Eq 16
#define Nn (Bq*Hq)        // 256 sequences
#define T 254             // Lq - 3 + 1
#define A 145             // E + 1 + 128 augmented channels
#define SIG_CH (A + A*A)  // 21170
#define KP 21184          // padded K (mult of 32), bf16 arrays
#define OUT 256

typedef __attribute__((ext_vector_type(8))) short short8;
typedef __attribute__((ext_vector_type(8))) unsigned short ushort8;
typedef __attribute__((ext_vector_type(4))) float floatx4;

static __device__ __forceinline__ unsigned short f2bf(float v) {
    unsigned int u = __float_as_uint(v);
    unsigned int r = (u + 0x7FFFu + ((u >> 16) & 1u)) >> 16;
    return (unsigned short)r;
}
static __device__ __forceinline__ float bf2f(unsigned short b) {
    return __uint_as_float(((unsigned int)b) << 16);
}

// ---------------------------------------------------------------------------
// Kernel F: FUSED augsig + wconv + out-init in ONE launch (independent block
// families; augsig first so the long poles start immediately, wconv/init
// stream through each CU's remaining block slot concurrently).
//   blocks [0,256):      augsig (conv B-frags self-converted from fp32 w1/w2)
//   blocks [256,1580):   wconv  W[k][o] -> wt_hi/lo[o][KP] (coalesced stores)
//   blocks [1580,1836):  out[n][o] = lin_b[o]
// ---------------------------------------------------------------------------
#define MDS 40    // M/D row stride (ushorts)
#define OS3 36    // outs row stride (floats)
#define XIS 72    // xim/a1 row stride (ushorts)

__global__ __launch_bounds__(256) void fused_kernel(
    const float* __restrict__ q,
    const float* __restrict__ w1, const float* __restrict__ b1,
    const float* __restrict__ w2, const float* __restrict__ b2,
    const float* __restrict__ W,  const float* __restrict__ lb,
    unsigned short* __restrict__ sig_hi, unsigned short* __restrict__ sig_lo,
    unsigned short* __restrict__ wt_hi,  unsigned short* __restrict__ wt_lo,
    float* __restrict__ out)
{
    __shared__ __align__(16) unsigned short mdb[3*160*MDS]; // 38.4KB
    __shared__ __align__(16) float outs[A*OS3];             // 20.9KB
    __shared__ __align__(16) float xsc[36*16];              // 2.3KB
    __shared__ __align__(16) float b1s[64];
    __shared__ __align__(16) float b2s[128];

    const int tid = threadIdx.x;
    const int bid = blockIdx.x;

    if (bid >= 1580) {                 // ---- out init
        out[(bid - 1580)*256 + tid] = lb[tid];
        return;
    }

    if (bid >= 256) {                  // ---- wconv (reuses mdb as fp32 tile)
        float* ls = (float*)mdb;       // [64][65] = 16.6KB of the 38.4KB
        const int wid = bid - 256;
        const int k0 = (wid % 331) * 64;
        const int o0 = (wid / 331) * 64;

        #pragma unroll
        for (int p = 0; p < 16; ++p) {
            int idx = tid + p*256;
            int kk = idx >> 6, oo = idx & 63;
            int k = k0 + kk;
            ls[kk*65 + oo] = (k < SIG_CH) ? W[(long)k*OUT + o0 + oo] : 0.f;
        }
        __syncthreads();

        const int ob = tid >> 3;
        const int kq = (tid & 7) * 8;
        #pragma unroll
        for (int p = 0; p < 2; ++p) {
            int o = p*32 + ob;
            unsigned short hbuf[8], lbuf[8];
            #pragma unroll
            for (int j = 0; j < 8; ++j) {
                float v = ls[(kq + j)*65 + o];
                unsigned short hb = f2bf(v);
                hbuf[j] = hb;
                lbuf[j] = f2bf(v - bf2f(hb));
            }
            long off = (long)(o0 + o)*KP + k0 + kq;
            *(ushort8*)(wt_hi + off) = *(ushort8*)hbuf;
            *(ushort8*)(wt_lo + off) = *(ushort8*)lbuf;
        }
        return;
    }

    // ======================= augsig path (bid < 256) =======================
    unsigned short* Mh = mdb;
    unsigned short* Ml = mdb + 160*MDS;
    unsigned short* Dh = mdb + 2*160*MDS;
    unsigned short* ximh = mdb;
    unsigned short* ximl = mdb + 3456;
    unsigned short* a1h  = mdb + 6912;
    unsigned short* a1l  = mdb + 10368;

    const int n = bid;
    const int b = n >> 3, h = n & 7;

    const int lane = tid & 63;
    const int wv   = tid >> 6;
    const int frow = lane & 15;
    const int quad = lane >> 4;
    const int wm = wv & 1, wn = wv >> 1;

    if (tid < 64)  b1s[tid] = b1[tid];
    if (tid < 128) b2s[tid] = b2[tid];

    const float4* q4 = (const float4*)q + ((long)(b*Lq)*Hq + h)*4;
    const float inv253 = 1.0f / 253.0f;

    // ---- conv B-fragments: self-converted from fp32 w1/w2 (bit-identical
    // to the old wsplit path; 48 scalar L2-hot loads, once per block)
    short8 c1bh[2], c1bl[2];
    #pragma unroll
    for (int ks = 0; ks < 2; ++ks) {
        const int ccol = wv*16 + frow;
        unsigned short hbuf[8], lbuf[8];
        #pragma unroll
        for (int e = 0; e < 8; ++e) {
            int k = ks*32 + quad*8 + e;
            float v = (k < 48) ? w1[k*64 + ccol] : 0.f;
            unsigned short hb2 = f2bf(v);
            hbuf[e] = hb2; lbuf[e] = f2bf(v - bf2f(hb2));
        }
        c1bh[ks] = *(short8*)hbuf;
        c1bl[ks] = *(short8*)lbuf;
    }
    short8 c2bh[2][2], c2bl[2][2];
    #pragma unroll
    for (int nt = 0; nt < 2; ++nt)
        #pragma unroll
        for (int ks = 0; ks < 2; ++ks) {
            const int ccol = wv*32 + nt*16 + frow;
            unsigned short hbuf[8], lbuf[8];
            #pragma unroll
            for (int e = 0; e < 8; ++e) {
                int i = ks*32 + quad*8 + e;
                float v = w2[i*128 + ccol];
                unsigned short hb2 = f2bf(v);
                hbuf[e] = hb2; lbuf[e] = f2bf(v - bf2f(hb2));
            }
            c2bh[nt][ks] = *(short8*)hbuf;
            c2bl[nt][ks] = *(short8*)lbuf;
        }

    float a0 = 0.f, vlast = 0.f;

    floatx4 acc[5][5];
    #pragma unroll
    for (int i = 0; i < 5; ++i)
        #pragma unroll
        for (int j = 0; j < 5; ++j)
            acc[i][j] = (floatx4){0.f, 0.f, 0.f, 0.f};

    #pragma unroll 1
    for (int c = 0; c < 8; ++c) {
        const int t0 = c*32;

        // ---- stage x rows t0..t0+34 (clamped)
        if (tid < 140) {
            int r = tid >> 2, e4 = tid & 3;
            int t = t0 + r; if (t > 255) t = 255;
            *((float4*)xsc + (r*4 + e4)) = q4[t*32 + e4];
        }
        __syncthreads();   // B1

        // ---- im2col pack
        for (int idx = tid; idx < 48*8; idx += 256) {
            int r = idx >> 3, g = idx & 7;
            unsigned short hh[8], ll[8];
            if (r <= 32 && g < 6) {
                const float* src = &xsc[r*16 + g*8];
                #pragma unroll
                for (int e = 0; e < 8; ++e) {
                    float v = src[e];
                    unsigned short hbv = f2bf(v);
                    hh[e] = hbv; ll[e] = f2bf(v - bf2f(hbv));
                }
            } else {
                #pragma unroll
                for (int e = 0; e < 8; ++e) { hh[e] = 0; ll[e] = 0; }
            }
            *(ushort8*)&ximh[r*XIS + g*8] = *(ushort8*)hh;
            *(ushort8*)&ximl[r*XIS + g*8] = *(ushort8*)ll;
        }
        __syncthreads();   // B2

        // ---- conv1 MFMA
        {
            short8 ah[3][2], al[3][2];
            #pragma unroll
            for (int mt = 0; mt < 3; ++mt)
                #pragma unroll
                for (int ks = 0; ks < 2; ++ks) {
                    int ar = (mt*16 + frow)*XIS + ks*32 + quad*8;
                    ah[mt][ks] = *(const short8*)&ximh[ar];
                    al[mt][ks] = *(const short8*)&ximl[ar];
                }
            floatx4 acc1[3];
            #pragma unroll
            for (int mt = 0; mt < 3; ++mt) acc1[mt] = (floatx4){0.f,0.f,0.f,0.f};
            #pragma unroll
            for (int mt = 0; mt < 3; ++mt)
                #pragma unroll
                for (int ks = 0; ks < 2; ++ks) {
                    acc1[mt] = __builtin_amdgcn_mfma_f32_16x16x32_bf16(ah[mt][ks], c1bh[ks], acc1[mt], 0,0,0);
                    acc1[mt] = __builtin_amdgcn_mfma_f32_16x16x32_bf16(ah[mt][ks], c1bl[ks], acc1[mt], 0,0,0);
                    acc1[mt] = __builtin_amdgcn_mfma_f32_16x16x32_bf16(al[mt][ks], c1bh[ks], acc1[mt], 0,0,0);
                }
            const int cc = wv*16 + frow;
            const float bias = b1s[cc];
            #pragma unroll
            for (int mt = 0; mt < 3; ++mt)
                #pragma unroll
                for (int e = 0; e < 4; ++e) {
                    int t = mt*16 + quad*4 + e;
                    float v = acc1[mt][e] + bias;
                    unsigned short hbv = f2bf(v);
                    a1h[t*XIS + cc] = hbv;
                    a1l[t*XIS + cc] = f2bf(v - bf2f(hbv));
                }
        }
        __syncthreads();   // B3

        // ---- conv2 MFMA
        {
            short8 ah[3][2], al[3][2];
            #pragma unroll
            for (int mt = 0; mt < 3; ++mt)
                #pragma unroll
                for (int ks = 0; ks < 2; ++ks) {
                    int ar = (mt*16 + frow)*XIS + ks*32 + quad*8;
                    ah[mt][ks] = *(const short8*)&a1h[ar];
                    al[mt][ks] = *(const short8*)&a1l[ar];
                }
            floatx4 acc2[3][2];
            #pragma unroll
            for (int mt = 0; mt < 3; ++mt)
                #pragma unroll
                for (int nt = 0; nt < 2; ++nt)
                    acc2[mt][nt] = (floatx4){0.f,0.f,0.f,0.f};
            #pragma unroll
            for (int mt = 0; mt < 3; ++mt)
                #pragma unroll
                for (int nt = 0; nt < 2; ++nt)
                    #pragma unroll
                    for (int ks = 0; ks < 2; ++ks) {
                        acc2[mt][nt] = __builtin_amdgcn_mfma_f32_16x16x32_bf16(ah[mt][ks], c2bh[nt][ks], acc2[mt][nt], 0,0,0);
                        acc2[mt][nt] = __builtin_amdgcn_mfma_f32_16x16x32_bf16(ah[mt][ks], c2bl[nt][ks], acc2[mt][nt], 0,0,0);
                        acc2[mt][nt] = __builtin_amdgcn_mfma_f32_16x16x32_bf16(al[mt][ks], c2bh[nt][ks], acc2[mt][nt], 0,0,0);
                    }
            #pragma unroll
            for (int mt = 0; mt < 3; ++mt)
                #pragma unroll
                for (int nt = 0; nt < 2; ++nt) {
                    int cc = wv*32 + nt*16 + frow;
                    float bias = b2s[cc];
                    int tb = mt*16 + quad*4;
                    if (tb <= 32) {
                        float4 vv;
                        vv.x = fmaxf(acc2[mt][nt][0] + bias, 0.f);
                        vv.y = fmaxf(acc2[mt][nt][1] + bias, 0.f);
                        vv.z = fmaxf(acc2[mt][nt][2] + bias, 0.f);
                        vv.w = fmaxf(acc2[mt][nt][3] + bias, 0.f);
                        *(float4*)&outs[(17 + cc)*OS3 + tb] = vv;
                    }
                }
        }
        for (int idx = tid; idx < 17*33; idx += 256) {
            int ch = idx / 33, tt = idx - ch*33;
            float val = (ch < 16) ? xsc[(tt+2)*16 + ch] : (float)(t0+tt)*inv253;
            outs[ch*OS3 + tt] = val;
        }
        __syncthreads();   // B4

        // ---- M/D pack
        if (tid < 160) {
            unsigned short mh[32], ml[32], dh[32];
            if (tid < A) {
                float v[33];
                #pragma unroll
                for (int i = 0; i < 8; ++i)
                    *(float4*)&v[i*4] = *(const float4*)&outs[tid*OS3 + i*4];
                v[32] = outs[tid*OS3 + 32];
                if (c == 0) a0 = v[0];
                if (c == 7) vlast = v[29];
                #pragma unroll
                for (int tl = 0; tl < 32; ++tl) {
                    bool valid = (t0 + tl) <= 252;
                    float x0 = v[tl], x1 = v[tl+1];
                    float d = valid ? (x1 - x0) : 0.f;
                    float m = valid ? (0.5f*(x0 + x1) - a0) : 0.f;
                    unsigned short hbv = f2bf(m);
                    mh[tl] = hbv; ml[tl] = f2bf(m - bf2f(hbv));
                    dh[tl] = f2bf(d);
                }
            } else {
                #pragma unroll
                for (int tl = 0; tl < 32; ++tl) { mh[tl]=0; ml[tl]=0; dh[tl]=0; }
            }
            #pragma unroll
            for (int pp = 0; pp < 4; ++pp) {
                *(ushort8*)&Mh[tid*MDS + pp*8] = *(ushort8*)&mh[pp*8];
                *(ushort8*)&Ml[tid*MDS + pp*8] = *(ushort8*)&ml[pp*8];
                *(ushort8*)&Dh[tid*MDS + pp*8] = *(ushort8*)&dh[pp*8];
            }
        }
        __syncthreads();   // B5

        // ---- signature MFMA
        {
            short8 afh[5], afl[5], bfh[5];
            #pragma unroll
            for (int i = 0; i < 5; ++i) {
                int ar = (wm*80 + i*16 + frow)*MDS + quad*8;
                int br = (wn*80 + i*16 + frow)*MDS + quad*8;
                afh[i] = *(const short8*)&Mh[ar];
                afl[i] = *(const short8*)&Ml[ar];
                bfh[i] = *(const short8*)&Dh[br];
            }
            #pragma unroll
            for (int mt = 0; mt < 5; ++mt)
                #pragma unroll
                for (int nt = 0; nt < 5; ++nt) {
                    acc[mt][nt] = __builtin_amdgcn_mfma_f32_16x16x32_bf16(
                        afh[mt], bfh[nt], acc[mt][nt], 0, 0, 0);
                    acc[mt][nt] = __builtin_amdgcn_mfma_f32_16x16x32_bf16(
                        afl[mt], bfh[nt], acc[mt][nt], 0, 0, 0);
                }
        }
        __syncthreads();   // B6
    }

    // ---- epilogue
    unsigned short* sh = sig_hi + (long)n*KP;
    unsigned short* sl = sig_lo + (long)n*KP;
    if (tid < A) {
        float v = vlast - a0;
        unsigned short hbv = f2bf(v);
        sh[tid] = hbv;
        sl[tid] = f2bf(v - bf2f(hbv));
    }
    if (tid >= 160 && tid < 160 + (KP - SIG_CH)) {
        sh[SIG_CH + tid - 160] = 0;
        sl[SIG_CH + tid - 160] = 0;
    }
    #pragma unroll
    for (int mt = 0; mt < 5; ++mt)
        #pragma unroll
        for (int nt = 0; nt < 5; ++nt) {
            int j = wn*80 + nt*16 + frow;
            int ib = wm*80 + mt*16 + quad*4;
            #pragma unroll
            for (int e = 0; e < 4; ++e) {
                int i = ib + e;
                if (i < A && j < A) {
                    float v = acc[mt][nt][e];
                    unsigned short hbv = f2bf(v);
                    sh[A + i*A + j] = hbv;
                    sl[A + i*A + j] = f2bf(v - bf2f(hbv));
                }
            }
        }
}

// ---------------------------------------------------------------------------
// Kernel C: MFMA bf16 split GEMM, 128n x 64o tiles, grid (4,2,61).
// Epilogue atomicAdds into bias-initialized out.
// ---------------------------------------------------------------------------
#define SPLITK 61
#define KC 352
#define NSTEP (KC/32)   // 11
#define LDA 40

__global__ __launch_bounds__(256) void gemm_kernel(
    const unsigned short* __restrict__ sig_hi, const unsigned short* __restrict__ sig_lo,
    const unsigned short* __restrict__ wt_hi,  const unsigned short* __restrict__ wt_lo,
    float* __restrict__ out)
{
    __shared__ __align__(16) unsigned short Ah[128*LDA];
    __shared__ __align__(16) unsigned short Al[128*LDA];
    __shared__ __align__(16) unsigned short Bh[64*LDA];
    __shared__ __align__(16) unsigned short Bl[64*LDA];

    const int tid = threadIdx.x;
    const int o0 = blockIdx.x * 64;
    const int n0 = blockIdx.y * 128;
    const int z  = blockIdx.z;
    const int k0 = z * KC;

    const int lane = tid & 63;
    const int w    = tid >> 6;
    const int wm   = w & 1;
    const int wn   = w >> 1;
    const int frow = lane & 15;
    const int quad = lane >> 4;

    const int srowA = tid >> 1;
    const int khA   = (tid & 1) * 16;
    const int srowB = tid >> 2;
    const int kqB   = (tid & 3) * 8;

    const unsigned short* gAh = sig_hi + (long)(n0 + srowA)*KP;
    const unsigned short* gAl = sig_lo + (long)(n0 + srowA)*KP;
    const unsigned short* gBh = wt_hi  + (long)(o0 + srowB)*KP;
    const unsigned short* gBl = wt_lo  + (long)(o0 + srowB)*KP;

    ushort8 rah[2], ral[2], rbh, rbl;
    const ushort8 z8 = {0,0,0,0,0,0,0,0};

    #define GLOAD(s)                                                          \
        {                                                                     \
            int kb = k0 + (s)*32;                                             \
            if (kb < KP) {                                                    \
                rah[0] = *(const ushort8*)(gAh + kb + khA);                   \
                rah[1] = *(const ushort8*)(gAh + kb + khA + 8);               \
                ral[0] = *(const ushort8*)(gAl + kb + khA);                   \
                ral[1] = *(const ushort8*)(gAl + kb + khA + 8);               \
                rbh    = *(const ushort8*)(gBh + kb + kqB);                   \
                rbl    = *(const ushort8*)(gBl + kb + kqB);                   \
            } else {                                                          \
                rah[0]=z8; rah[1]=z8; ral[0]=z8; ral[1]=z8;                   \
                rbh=z8; rbl=z8;                                               \
            }                                                                 \
        }

    #define LSTORE()                                                          \
        {                                                                     \
            int oA = srowA*LDA + khA;                                         \
            *(ushort8*)(Ah + oA)     = rah[0];                                \
            *(ushort8*)(Ah + oA + 8) = rah[1];                                \
            *(ushort8*)(Al + oA)     = ral[0];                                \
            *(ushort8*)(Al + oA + 8) = ral[1];                                \
            int oB = srowB*LDA + kqB;                                         \
            *(ushort8*)(Bh + oB) = rbh;                                       \
            *(ushort8*)(Bl + oB) = rbl;                                       \
        }

    floatx4 acc[4][2];
    #pragma unroll
    for (int i = 0; i < 4; ++i)
        #pragma unroll
        for (int j = 0; j < 2; ++j)
            acc[i][j] = (floatx4){0.f, 0.f, 0.f, 0.f};

    GLOAD(0);
    LSTORE();
    __syncthreads();

    for (int s = 0; s < NSTEP; ++s) {
        if (s < NSTEP-1) GLOAD(s+1);

        short8 afh[4], afl[4], bfh[2], bfl[2];
        const int aoff = (wm*64 + frow)*LDA + quad*8;
        const int boff = (wn*32 + frow)*LDA + quad*8;
        #pragma unroll
        for (int tI = 0; tI < 4; ++tI) {
            afh[tI] = *(const short8*)(Ah + aoff + tI*16*LDA);
            afl[tI] = *(const short8*)(Al + aoff + tI*16*LDA);
        }
        #pragma unroll
        for (int tI = 0; tI < 2; ++tI) {
            bfh[tI] = *(const short8*)(Bh + boff + tI*16*LDA);
            bfl[tI] = *(const short8*)(Bl + boff + tI*16*LDA);
        }
        #pragma unroll
        for (int mt = 0; mt < 4; ++mt)
            #pragma unroll
            for (int nt = 0; nt < 2; ++nt) {
                acc[mt][nt] = __builtin_amdgcn_mfma_f32_16x16x32_bf16(
                    afh[mt], bfh[nt], acc[mt][nt], 0, 0, 0);
                acc[mt][nt] = __builtin_amdgcn_mfma_f32_16x16x32_bf16(
                    afh[mt], bfl[nt], acc[mt][nt], 0, 0, 0);
                acc[mt][nt] = __builtin_amdgcn_mfma_f32_16x16x32_bf16(
                    afl[mt], bfh[nt], acc[mt][nt], 0, 0, 0);
            }
        __syncthreads();
        if (s < NSTEP-1) {
            LSTORE();
            __syncthreads();
        }
    }

    #pragma unroll
    for (int mt = 0; mt < 4; ++mt)
        #pragma unroll
        for (int nt = 0; nt < 2; ++nt) {
            int col = o0 + wn*32 + nt*16 + frow;
            int rbase = n0 + wm*64 + mt*16 + quad*4;
            #pragma unroll
            for (int e = 0; e < 4; ++e)
                atomicAdd(&out[(long)(rbase + e)*OUT + col], acc[mt][nt][e]);
        }
}

// ---------------------------------------------------------------------------
extern "C" void kernel_launch(void* const* d_in, const int* in_sizes, int n_in,
                              void* d_out, int out_size, void* d_ws, size_t ws_size,
                              hipStream_t stream) {
    const float* q  = (const float*)d_in[0];
    const float* w1 = (const float*)d_in[4];
    const float* b1 = (const float*)d_in[5];
    const float* w2 = (const float*)d_in[6];
    const float* b2 = (const float*)d_in[7];
    const float* lw = (const float*)d_in[8];
    const float* lb = (const float*)d_in[9];
    float* out = (float*)d_out;

    // ws layout — 43.4 MB (within proven 59.4 MB envelope):
    //   [0]          sig_hi (10,846,208)
    //   [10846208]   sig_lo (10,846,208)
    //   [21692416]   wt_hi  (10,846,208)
    //   [32538624]   wt_lo  (10,846,208)
    char* ws = (char*)d_ws;
    unsigned short* sig_hi  = (unsigned short*)ws;
    unsigned short* sig_lo  = (unsigned short*)(ws + 10846208);
    unsigned short* wt_hi   = (unsigned short*)(ws + 21692416);
    unsigned short* wt_lo   = (unsigned short*)(ws + 32538624);

    fused_kernel<<<1836, 256, 0, stream>>>(q, w1, b1, w2, b2, lw, lb,
                                           sig_hi, sig_lo, wt_hi, wt_lo, out);
    gemm_kernel<<<dim3(4, 2, SPLITK), 256, 0, stream>>>(sig_hi, sig_lo, wt_hi, wt_lo, out);
}

// Round 21
// 167.452 us; speedup vs baseline: 1.0428x; 1.0428x over previous
//
#include <hip/hip_runtime.h>
#include <hip/hip_bf16.h>

// Problem constants
#define Bq 32
#define Lq 256
#define Hq 8
#define Eq 16
#define Nn (Bq*Hq)        // 256 sequences
#define T 254             // Lq - 3 + 1
#define A 145             // E + 1 + 128 augmented channels
#define SIG_CH (A + A*A)  // 21170
#define KP 21184          // padded K (mult of 32), bf16 arrays
#define OUT 256

typedef __attribute__((ext_vector_type(8))) short short8;
typedef __attribute__((ext_vector_type(8))) unsigned short ushort8;
typedef __attribute__((ext_vector_type(4))) float floatx4;

static __device__ __forceinline__ unsigned short f2bf(float v) {
    unsigned int u = __float_as_uint(v);
    unsigned int r = (u + 0x7FFFu + ((u >> 16) & 1u)) >> 16;
    return (unsigned short)r;
}
static __device__ __forceinline__ float bf2f(unsigned short b) {
    return __uint_as_float(((unsigned int)b) << 16);
}

// ---------------------------------------------------------------------------
// Kernel W+P merged: blocks 0..1323 = wconv (W -> wt_hi/lo transposed split);
// blocks 1324..1371 = wsplit (w1/w2 -> w1im/w2t bf16 split).
// ---------------------------------------------------------------------------
__global__ __launch_bounds__(256) void wprep_kernel(
    const float* __restrict__ W,
    unsigned short* __restrict__ wt_hi, unsigned short* __restrict__ wt_lo,
    const float* __restrict__ w1, const float* __restrict__ w2,
    unsigned short* __restrict__ w1im_hi, unsigned short* __restrict__ w1im_lo,
    unsigned short* __restrict__ w2t_hi,  unsigned short* __restrict__ w2t_lo)
{
    const int tid = threadIdx.x;
    if (blockIdx.x >= 1324) {
        int idx = (blockIdx.x - 1324)*256 + tid;   // 0..12287
        if (idx < 4096) {
            int c = idx & 63, k = idx >> 6;
            float v = (k < 48) ? w1[k*64 + c] : 0.f;
            unsigned short hb = f2bf(v);
            w1im_hi[c*64 + k] = hb;
            w1im_lo[c*64 + k] = f2bf(v - bf2f(hb));
        } else {
            int j = idx - 4096;
            int c = j & 127, i = j >> 7;
            float v = w2[i*128 + c];
            unsigned short hb = f2bf(v);
            w2t_hi[c*64 + i] = hb;
            w2t_lo[c*64 + i] = f2bf(v - bf2f(hb));
        }
        return;
    }

    __shared__ float ls[64][65];
    const int k0 = (blockIdx.x % 331) * 64;
    const int o0 = (blockIdx.x / 331) * 64;

    #pragma unroll
    for (int p = 0; p < 16; ++p) {
        int idx = tid + p*256;
        int kk = idx >> 6, oo = idx & 63;
        int k = k0 + kk;
        ls[kk][oo] = (k < SIG_CH) ? W[(long)k*OUT + o0 + oo] : 0.f;
    }
    __syncthreads();

    const int oo = tid >> 2;
    const int kq = (tid & 3) * 16;
    unsigned short hbuf[16], lbuf[16];
    #pragma unroll
    for (int j = 0; j < 16; ++j) {
        float v = ls[kq + j][oo];
        unsigned short hb = f2bf(v);
        hbuf[j] = hb;
        lbuf[j] = f2bf(v - bf2f(hb));
    }
    long off = (long)(o0 + oo)*KP + k0 + kq;
    *(ushort8*)(wt_hi + off)     = *(ushort8*)&hbuf[0];
    *(ushort8*)(wt_hi + off + 8) = *(ushort8*)&hbuf[8];
    *(ushort8*)(wt_lo + off)     = *(ushort8*)&lbuf[0];
    *(ushort8*)(wt_lo + off + 8) = *(ushort8*)&lbuf[8];
}

// ---------------------------------------------------------------------------
// Kernel AS: FUSED aug+sig (R14-proven form). One block per n,
// 256 thr = 4 waves. Per 32-t chunk: stage x -> im2col pack -> conv1 MFMA
// -> conv2 MFMA + ReLU -> outs -> M/D pack (M hi/lo, D hi) -> sig MFMA.
// ---------------------------------------------------------------------------
#define MDS 40    // M/D row stride (ushorts)
#define OS3 36    // outs row stride (floats)
#define XIS 72    // xim/a1 row stride (ushorts)

__global__ __launch_bounds__(256) void augsig_kernel(
    const float* __restrict__ q,
    const float* __restrict__ b1, const float* __restrict__ b2,
    const unsigned short* __restrict__ w1im_hi, const unsigned short* __restrict__ w1im_lo,
    const unsigned short* __restrict__ w2t_hi,  const unsigned short* __restrict__ w2t_lo,
    unsigned short* __restrict__ sig_hi, unsigned short* __restrict__ sig_lo)
{
    __shared__ __align__(16) unsigned short mdb[3*160*MDS]; // 38.4KB
    __shared__ __align__(16) float outs[A*OS3];             // 20.9KB
    __shared__ __align__(16) float xsc[36*16];              // 2.3KB
    __shared__ __align__(16) float b1s[64];
    __shared__ __align__(16) float b2s[128];

    unsigned short* Mh = mdb;
    unsigned short* Ml = mdb + 160*MDS;
    unsigned short* Dh = mdb + 2*160*MDS;
    unsigned short* ximh = mdb;
    unsigned short* ximl = mdb + 3456;
    unsigned short* a1h  = mdb + 6912;
    unsigned short* a1l  = mdb + 10368;

    const int tid = threadIdx.x;
    const int n = blockIdx.x;
    const int b = n >> 3, h = n & 7;

    const int lane = tid & 63;
    const int wv   = tid >> 6;
    const int frow = lane & 15;
    const int quad = lane >> 4;
    const int wm = wv & 1, wn = wv >> 1;

    if (tid < 64)  b1s[tid] = b1[tid];
    if (tid < 128) b2s[tid] = b2[tid];

    const float4* q4 = (const float4*)q + ((long)(b*Lq)*Hq + h)*4;
    const float inv253 = 1.0f / 253.0f;

    float a0 = 0.f, vlast = 0.f;

    floatx4 acc[5][5];
    #pragma unroll
    for (int i = 0; i < 5; ++i)
        #pragma unroll
        for (int j = 0; j < 5; ++j)
            acc[i][j] = (floatx4){0.f, 0.f, 0.f, 0.f};

    #pragma unroll 1
    for (int c = 0; c < 8; ++c) {
        const int t0 = c*32;

        if (tid < 140) {
            int r = tid >> 2, e4 = tid & 3;
            int t = t0 + r; if (t > 255) t = 255;
            *((float4*)xsc + (r*4 + e4)) = q4[t*32 + e4];
        }
        __syncthreads();   // B1

        for (int idx = tid; idx < 48*8; idx += 256) {
            int r = idx >> 3, g = idx & 7;
            unsigned short hh[8], ll[8];
            if (r <= 32 && g < 6) {
                const float* src = &xsc[r*16 + g*8];
                #pragma unroll
                for (int e = 0; e < 8; ++e) {
                    float v = src[e];
                    unsigned short hbv = f2bf(v);
                    hh[e] = hbv; ll[e] = f2bf(v - bf2f(hbv));
                }
            } else {
                #pragma unroll
                for (int e = 0; e < 8; ++e) { hh[e] = 0; ll[e] = 0; }
            }
            *(ushort8*)&ximh[r*XIS + g*8] = *(ushort8*)hh;
            *(ushort8*)&ximl[r*XIS + g*8] = *(ushort8*)ll;
        }
        __syncthreads();   // B2

        // conv1 MFMA
        {
            short8 ah[3][2], al[3][2];
            #pragma unroll
            for (int mt = 0; mt < 3; ++mt)
                #pragma unroll
                for (int ks = 0; ks < 2; ++ks) {
                    int ar = (mt*16 + frow)*XIS + ks*32 + quad*8;
                    ah[mt][ks] = *(const short8*)&ximh[ar];
                    al[mt][ks] = *(const short8*)&ximl[ar];
                }
            short8 bh[2], bl[2];
            #pragma unroll
            for (int ks = 0; ks < 2; ++ks) {
                int br = (wv*16 + frow)*64 + ks*32 + quad*8;
                bh[ks] = *(const short8*)(w1im_hi + br);
                bl[ks] = *(const short8*)(w1im_lo + br);
            }
            floatx4 acc1[3];
            #pragma unroll
            for (int mt = 0; mt < 3; ++mt) acc1[mt] = (floatx4){0.f,0.f,0.f,0.f};
            #pragma unroll
            for (int mt = 0; mt < 3; ++mt)
                #pragma unroll
                for (int ks = 0; ks < 2; ++ks) {
                    acc1[mt] = __builtin_amdgcn_mfma_f32_16x16x32_bf16(ah[mt][ks], bh[ks], acc1[mt], 0,0,0);
                    acc1[mt] = __builtin_amdgcn_mfma_f32_16x16x32_bf16(ah[mt][ks], bl[ks], acc1[mt], 0,0,0);
                    acc1[mt] = __builtin_amdgcn_mfma_f32_16x16x32_bf16(al[mt][ks], bh[ks], acc1[mt], 0,0,0);
                }
            const int cc = wv*16 + frow;
            const float bias = b1s[cc];
            #pragma unroll
            for (int mt = 0; mt < 3; ++mt)
                #pragma unroll
                for (int e = 0; e < 4; ++e) {
                    int t = mt*16 + quad*4 + e;
                    float v = acc1[mt][e] + bias;
                    unsigned short hbv = f2bf(v);
                    a1h[t*XIS + cc] = hbv;
                    a1l[t*XIS + cc] = f2bf(v - bf2f(hbv));
                }
        }
        __syncthreads();   // B3

        // conv2 MFMA
        {
            short8 ah[3][2], al[3][2];
            #pragma unroll
            for (int mt = 0; mt < 3; ++mt)
                #pragma unroll
                for (int ks = 0; ks < 2; ++ks) {
                    int ar = (mt*16 + frow)*XIS + ks*32 + quad*8;
                    ah[mt][ks] = *(const short8*)&a1h[ar];
                    al[mt][ks] = *(const short8*)&a1l[ar];
                }
            short8 bh[2][2], bl[2][2];
            #pragma unroll
            for (int nt = 0; nt < 2; ++nt)
                #pragma unroll
                for (int ks = 0; ks < 2; ++ks) {
                    int br = (wv*32 + nt*16 + frow)*64 + ks*32 + quad*8;
                    bh[nt][ks] = *(const short8*)(w2t_hi + br);
                    bl[nt][ks] = *(const short8*)(w2t_lo + br);
                }
            floatx4 acc2[3][2];
            #pragma unroll
            for (int mt = 0; mt < 3; ++mt)
                #pragma unroll
                for (int nt = 0; nt < 2; ++nt)
                    acc2[mt][nt] = (floatx4){0.f,0.f,0.f,0.f};
            #pragma unroll
            for (int mt = 0; mt < 3; ++mt)
                #pragma unroll
                for (int nt = 0; nt < 2; ++nt)
                    #pragma unroll
                    for (int ks = 0; ks < 2; ++ks) {
                        acc2[mt][nt] = __builtin_amdgcn_mfma_f32_16x16x32_bf16(ah[mt][ks], bh[nt][ks], acc2[mt][nt], 0,0,0);
                        acc2[mt][nt] = __builtin_amdgcn_mfma_f32_16x16x32_bf16(ah[mt][ks], bl[nt][ks], acc2[mt][nt], 0,0,0);
                        acc2[mt][nt] = __builtin_amdgcn_mfma_f32_16x16x32_bf16(al[mt][ks], bh[nt][ks], acc2[mt][nt], 0,0,0);
                    }
            #pragma unroll
            for (int mt = 0; mt < 3; ++mt)
                #pragma unroll
                for (int nt = 0; nt < 2; ++nt) {
                    int cc = wv*32 + nt*16 + frow;
                    float bias = b2s[cc];
                    int tb = mt*16 + quad*4;
                    if (tb <= 32) {
                        float4 vv;
                        vv.x = fmaxf(acc2[mt][nt][0] + bias, 0.f);
                        vv.y = fmaxf(acc2[mt][nt][1] + bias, 0.f);
                        vv.z = fmaxf(acc2[mt][nt][2] + bias, 0.f);
                        vv.w = fmaxf(acc2[mt][nt][3] + bias, 0.f);
                        *(float4*)&outs[(17 + cc)*OS3 + tb] = vv;
                    }
                }
        }
        for (int idx = tid; idx < 17*33; idx += 256) {
            int ch = idx / 33, tt = idx - ch*33;
            float val = (ch < 16) ? xsc[(tt+2)*16 + ch] : (float)(t0+tt)*inv253;
            outs[ch*OS3 + tt] = val;
        }
        __syncthreads();   // B4

        // M/D pack
        if (tid < 160) {
            unsigned short mh[32], ml[32], dh[32];
            if (tid < A) {
                float v[33];
                #pragma unroll
                for (int i = 0; i < 8; ++i)
                    *(float4*)&v[i*4] = *(const float4*)&outs[tid*OS3 + i*4];
                v[32] = outs[tid*OS3 + 32];
                if (c == 0) a0 = v[0];
                if (c == 7) vlast = v[29];
                #pragma unroll
                for (int tl = 0; tl < 32; ++tl) {
                    bool valid = (t0 + tl) <= 252;
                    float x0 = v[tl], x1 = v[tl+1];
                    float d = valid ? (x1 - x0) : 0.f;
                    float m = valid ? (0.5f*(x0 + x1) - a0) : 0.f;
                    unsigned short hbv = f2bf(m);
                    mh[tl] = hbv; ml[tl] = f2bf(m - bf2f(hbv));
                    dh[tl] = f2bf(d);
                }
            } else {
                #pragma unroll
                for (int tl = 0; tl < 32; ++tl) { mh[tl]=0; ml[tl]=0; dh[tl]=0; }
            }
            #pragma unroll
            for (int pp = 0; pp < 4; ++pp) {
                *(ushort8*)&Mh[tid*MDS + pp*8] = *(ushort8*)&mh[pp*8];
                *(ushort8*)&Ml[tid*MDS + pp*8] = *(ushort8*)&ml[pp*8];
                *(ushort8*)&Dh[tid*MDS + pp*8] = *(ushort8*)&dh[pp*8];
            }
        }
        __syncthreads();   // B5

        // signature MFMA
        {
            short8 afh[5], afl[5], bfh[5];
            #pragma unroll
            for (int i = 0; i < 5; ++i) {
                int ar = (wm*80 + i*16 + frow)*MDS + quad*8;
                int br = (wn*80 + i*16 + frow)*MDS + quad*8;
                afh[i] = *(const short8*)&Mh[ar];
                afl[i] = *(const short8*)&Ml[ar];
                bfh[i] = *(const short8*)&Dh[br];
            }
            #pragma unroll
            for (int mt = 0; mt < 5; ++mt)
                #pragma unroll
                for (int nt = 0; nt < 5; ++nt) {
                    acc[mt][nt] = __builtin_amdgcn_mfma_f32_16x16x32_bf16(
                        afh[mt], bfh[nt], acc[mt][nt], 0, 0, 0);
                    acc[mt][nt] = __builtin_amdgcn_mfma_f32_16x16x32_bf16(
                        afl[mt], bfh[nt], acc[mt][nt], 0, 0, 0);
                }
        }
    }

    // epilogue
    unsigned short* sh = sig_hi + (long)n*KP;
    unsigned short* sl = sig_lo + (long)n*KP;
    if (tid < A) {
        float v = vlast - a0;
        unsigned short hbv = f2bf(v);
        sh[tid] = hbv;
        sl[tid] = f2bf(v - bf2f(hbv));
    }
    if (tid >= 160 && tid < 160 + (KP - SIG_CH)) {
        sh[SIG_CH + tid - 160] = 0;
        sl[SIG_CH + tid - 160] = 0;
    }
    #pragma unroll
    for (int mt = 0; mt < 5; ++mt)
        #pragma unroll
        for (int nt = 0; nt < 5; ++nt) {
            int j = wn*80 + nt*16 + frow;
            int ib = wm*80 + mt*16 + quad*4;
            #pragma unroll
            for (int e = 0; e < 4; ++e) {
                int i = ib + e;
                if (i < A && j < A) {
                    float v = acc[mt][nt][e];
                    unsigned short hbv = f2bf(v);
                    sh[A + i*A + j] = hbv;
                    sl[A + i*A + j] = f2bf(v - bf2f(hbv));
                }
            }
        }
}

// ---------------------------------------------------------------------------
// Kernel C: MFMA bf16 split GEMM, retiled 128n x 64o, grid (4,2,61) = 488
// blocks (~2/CU, LDS 30.7KB). Writes part; reduce adds bias.
// ---------------------------------------------------------------------------
#define SPLITK 61
#define KC 352
#define NSTEP (KC/32)   // 11
#define LDA 40

__global__ __launch_bounds__(256) void gemm_kernel(
    const unsigned short* __restrict__ sig_hi, const unsigned short* __restrict__ sig_lo,
    const unsigned short* __restrict__ wt_hi,  const unsigned short* __restrict__ wt_lo,
    float* __restrict__ part)
{
    __shared__ __align__(16) unsigned short Ah[128*LDA];
    __shared__ __align__(16) unsigned short Al[128*LDA];
    __shared__ __align__(16) unsigned short Bh[64*LDA];
    __shared__ __align__(16) unsigned short Bl[64*LDA];

    const int tid = threadIdx.x;
    const int o0 = blockIdx.x * 64;
    const int n0 = blockIdx.y * 128;
    const int z  = blockIdx.z;
    const int k0 = z * KC;

    const int lane = tid & 63;
    const int w    = tid >> 6;
    const int wm   = w & 1;          // n half (64 rows)
    const int wn   = w >> 1;         // o half (32 cols)
    const int frow = lane & 15;
    const int quad = lane >> 4;

    const int srowA = tid >> 1;
    const int khA   = (tid & 1) * 16;
    const int srowB = tid >> 2;
    const int kqB   = (tid & 3) * 8;

    const unsigned short* gAh = sig_hi + (long)(n0 + srowA)*KP;
    const unsigned short* gAl = sig_lo + (long)(n0 + srowA)*KP;
    const unsigned short* gBh = wt_hi  + (long)(o0 + srowB)*KP;
    const unsigned short* gBl = wt_lo  + (long)(o0 + srowB)*KP;

    ushort8 rah[2], ral[2], rbh, rbl;
    const ushort8 z8 = {0,0,0,0,0,0,0,0};

    #define GLOAD(s)                                                          \
        {                                                                     \
            int kb = k0 + (s)*32;                                             \
            if (kb < KP) {                                                    \
                rah[0] = *(const ushort8*)(gAh + kb + khA);                   \
                rah[1] = *(const ushort8*)(gAh + kb + khA + 8);               \
                ral[0] = *(const ushort8*)(gAl + kb + khA);                   \
                ral[1] = *(const ushort8*)(gAl + kb + khA + 8);               \
                rbh    = *(const ushort8*)(gBh + kb + kqB);                   \
                rbl    = *(const ushort8*)(gBl + kb + kqB);                   \
            } else {                                                          \
                rah[0]=z8; rah[1]=z8; ral[0]=z8; ral[1]=z8;                   \
                rbh=z8; rbl=z8;                                               \
            }                                                                 \
        }

    #define LSTORE()                                                          \
        {                                                                     \
            int oA = srowA*LDA + khA;                                         \
            *(ushort8*)(Ah + oA)     = rah[0];                                \
            *(ushort8*)(Ah + oA + 8) = rah[1];                                \
            *(ushort8*)(Al + oA)     = ral[0];                                \
            *(ushort8*)(Al + oA + 8) = ral[1];                                \
            int oB = srowB*LDA + kqB;                                         \
            *(ushort8*)(Bh + oB) = rbh;                                       \
            *(ushort8*)(Bl + oB) = rbl;                                       \
        }

    floatx4 acc[4][2];
    #pragma unroll
    for (int i = 0; i < 4; ++i)
        #pragma unroll
        for (int j = 0; j < 2; ++j)
            acc[i][j] = (floatx4){0.f, 0.f, 0.f, 0.f};

    GLOAD(0);
    LSTORE();
    __syncthreads();

    for (int s = 0; s < NSTEP; ++s) {
        if (s < NSTEP-1) GLOAD(s+1);

        short8 afh[4], afl[4], bfh[2], bfl[2];
        const int aoff = (wm*64 + frow)*LDA + quad*8;
        const int boff = (wn*32 + frow)*LDA + quad*8;
        #pragma unroll
        for (int tI = 0; tI < 4; ++tI) {
            afh[tI] = *(const short8*)(Ah + aoff + tI*16*LDA);
            afl[tI] = *(const short8*)(Al + aoff + tI*16*LDA);
        }
        #pragma unroll
        for (int tI = 0; tI < 2; ++tI) {
            bfh[tI] = *(const short8*)(Bh + boff + tI*16*LDA);
            bfl[tI] = *(const short8*)(Bl + boff + tI*16*LDA);
        }
        #pragma unroll
        for (int mt = 0; mt < 4; ++mt)
            #pragma unroll
            for (int nt = 0; nt < 2; ++nt) {
                acc[mt][nt] = __builtin_amdgcn_mfma_f32_16x16x32_bf16(
                    afh[mt], bfh[nt], acc[mt][nt], 0, 0, 0);
                acc[mt][nt] = __builtin_amdgcn_mfma_f32_16x16x32_bf16(
                    afh[mt], bfl[nt], acc[mt][nt], 0, 0, 0);
                acc[mt][nt] = __builtin_amdgcn_mfma_f32_16x16x32_bf16(
                    afl[mt], bfh[nt], acc[mt][nt], 0, 0, 0);
            }
        __syncthreads();
        if (s < NSTEP-1) {
            LSTORE();
            __syncthreads();
        }
    }

    float* pz = part + (long)z * (Nn*OUT);
    #pragma unroll
    for (int mt = 0; mt < 4; ++mt)
        #pragma unroll
        for (int nt = 0; nt < 2; ++nt) {
            int col = o0 + wn*32 + nt*16 + frow;
            int rbase = n0 + wm*64 + mt*16 + quad*4;
            #pragma unroll
            for (int e = 0; e < 4; ++e)
                pz[(long)(rbase + e)*OUT + col] = acc[mt][nt][e];
        }
}

// ---------------------------------------------------------------------------
// Kernel D: out[n][o] = lin_b[o] + sum_z part[z][n][o]
// ---------------------------------------------------------------------------
__global__ __launch_bounds__(256) void reduce_kernel(
    const float* __restrict__ part, const float* __restrict__ lb,
    float* __restrict__ out)
{
    int idx = blockIdx.x * 256 + threadIdx.x;
    float s = lb[idx & 255];
    #pragma unroll 8
    for (int z = 0; z < SPLITK; ++z)
        s += part[(long)z * (Nn*OUT) + idx];
    out[idx] = s;
}

// ---------------------------------------------------------------------------
extern "C" void kernel_launch(void* const* d_in, const int* in_sizes, int n_in,
                              void* d_out, int out_size, void* d_ws, size_t ws_size,
                              hipStream_t stream) {
    const float* q  = (const float*)d_in[0];
    const float* w1 = (const float*)d_in[4];
    const float* b1 = (const float*)d_in[5];
    const float* w2 = (const float*)d_in[6];
    const float* b2 = (const float*)d_in[7];
    const float* lw = (const float*)d_in[8];
    const float* lb = (const float*)d_in[9];
    float* out = (float*)d_out;

    // ws layout — 59.4 MB (proven envelope):
    //   [0]          sig_hi (10,846,208)
    //   [10846208]   sig_lo (10,846,208)
    //   [21692416]   wt_hi  (10,846,208)
    //   [32538624]   wt_lo  (10,846,208)
    //   [43384832]   part   (15,990,784)  ends 59,375,616
    //     w1im/w2t (48KB) live at part base until gemm overwrites (dead then)
    char* ws = (char*)d_ws;
    unsigned short* sig_hi  = (unsigned short*)ws;
    unsigned short* sig_lo  = (unsigned short*)(ws + 10846208);
    unsigned short* wt_hi   = (unsigned short*)(ws + 21692416);
    unsigned short* wt_lo   = (unsigned short*)(ws + 32538624);
    float*          part    = (float*)(ws + 43384832);
    unsigned short* w1im_hi = (unsigned short*)(ws + 43384832);
    unsigned short* w1im_lo = (unsigned short*)(ws + 43384832 + 8192);
    unsigned short* w2t_hi  = (unsigned short*)(ws + 43384832 + 16384);
    unsigned short* w2t_lo  = (unsigned short*)(ws + 43384832 + 32768);

    wprep_kernel<<<1372, 256, 0, stream>>>(lw, wt_hi, wt_lo,
                                           w1, w2, w1im_hi, w1im_lo, w2t_hi, w2t_lo);
    augsig_kernel<<<Nn, 256, 0, stream>>>(q, b1, b2, w1im_hi, w1im_lo, w2t_hi, w2t_lo, sig_hi, sig_lo);
    gemm_kernel<<<dim3(4, 2, SPLITK), 256, 0, stream>>>(sig_hi, sig_lo, wt_hi, wt_lo, part);
    reduce_kernel<<<(Nn*OUT)/256, 256, 0, stream>>>(part, lb, out);
}